// Round 10
// baseline (941.150 us; speedup 1.0000x reference)
//
#include <hip/hip_runtime.h>
#include <hip/hip_bf16.h>

// ---------------------------------------------------------------------------
// RNN_20572893348005: 2-layer tanh RNN, B=64 T=1024 D=128 H=256, out [B,H,T]
//
// v11 = v10 with the scan lane layout rebuilt against the measured LDS
// return-bandwidth bound (v10: 1613 cy/step ~= 8 waves x 16 KB broadcast
// h-reads through the ~128B/cy return path).
// Scan layout: M=2 outputs/lane x K-split=4. Lane l, wave wv:
//   jp = wv*16+(l&15) -> outputs 2jp,2jp+1;  kq = l>>4 -> K range [64kq,64kq+64)
//   h-read: 8 uint4 (128 B) from padded hbuf (quarter stride 144 B -> the 4
//   distinct addresses/instr hit disjoint bank quads); 32 dot2 (4 chains);
//   reduce: shfl_xor 16 then 32; kq0 writes hbuf', kq1 writes stage.
//   Weights: 16 uint4 = 64 VGPRs (v10-proven arch-resident regime).
// Traffic: 64 KB/step/CU (~512 cy) vs v10's 128 KB (~1024-1536 cy).
// Everything else identical to v10 (verified): mega roles scan0(d)|scan1(d-2)
// |proj0(d+1)|proj1(d-1)|transpose(d-3), all-waves-alive barrier discipline,
// raw lgkmcnt-only barrier, LDS xw-stage with in-place h overwrite, bulk
// coalesced copies, s_setprio(1) on scan blocks.
// ---------------------------------------------------------------------------

#define B_ 64
#define T_ 1024
#define D_ 128
#define H_ 256
#define TCMAX 128              // LDS stage = TCMAX*H*2 = 64 KB
#define HBQ 72                 // padded h-quarter stride in f16 (64 data + 8 pad)

typedef _Float16 half2_t __attribute__((ext_vector_type(2)));

__device__ __forceinline__ float bf2f(unsigned short u) {
    union { unsigned int i; float f; } v;
    v.i = ((unsigned int)u) << 16;
    return v.f;
}

__device__ __forceinline__ unsigned int cvt2_bf16_to_f16(unsigned int u) {
    union { float f; unsigned int i; } a, b;
    a.i = u << 16;
    b.i = u & 0xFFFF0000u;
    union { _Float16 h[2]; unsigned int u; } r;
    r.h[0] = (_Float16)a.f;
    r.h[1] = (_Float16)b.f;
    return r.u;
}

__device__ __forceinline__ uint4 cvt8_bf16_to_f16(uint4 v) {
    uint4 r;
    r.x = cvt2_bf16_to_f16(v.x);
    r.y = cvt2_bf16_to_f16(v.y);
    r.z = cvt2_bf16_to_f16(v.z);
    r.w = cvt2_bf16_to_f16(v.w);
    return r;
}

__device__ __forceinline__ float dot2(unsigned int a, unsigned int b, float c) {
    union { unsigned int u; half2_t h; } ua, ub;
    ua.u = a; ub.u = b;
#if defined(__HIP_DEVICE_COMPILE__) && __has_builtin(__builtin_amdgcn_fdot2)
    return __builtin_amdgcn_fdot2(ua.h, ub.h, c, false);
#else
    return c + (float)ua.h.x * (float)ub.h.x + (float)ua.h.y * (float)ub.h.y;
#endif
}

// branch-free tanh: (e^{2x}-1)/(e^{2x}+1) via exp2 + rcp; saturates correctly.
__device__ __forceinline__ float fast_tanh(float x) {
#if defined(__HIP_DEVICE_COMPILE__) && __has_builtin(__builtin_amdgcn_exp2f)
    float e = __builtin_amdgcn_exp2f(x * 2.885390081777927f);
#else
    float e = __expf(2.0f * x);
#endif
#if defined(__HIP_DEVICE_COMPILE__) && __has_builtin(__builtin_amdgcn_rcpf)
    return 1.0f - 2.0f * __builtin_amdgcn_rcpf(e + 1.0f);
#else
    return 1.0f - 2.0f / (e + 1.0f);
#endif
}

// raw workgroup barrier: LDS ordering only (no vmcnt drain). v6-v10-proven.
// Executed by ALL waves of the block (no exited waves - the v9 hazard).
__device__ __forceinline__ void lds_barrier() {
    asm volatile("s_waitcnt lgkmcnt(0)\n\ts_barrier" ::: "memory");
}

// ---- dtype detection ------------------------------------------------------
__global__ void detect_dtype(const unsigned short* __restrict__ w, int* __restrict__ flag) {
    if (threadIdx.x == 0 && blockIdx.x == 0) {
        int f = 0;
        for (int i = 0; i < 512; ++i) {
            unsigned e = (w[i] >> 7) & 0xFF;
            if (e >= 127) f = 1;
        }
        *flag = f;
    }
}

// ---- prep: weights (bf16|f32) -> f16, bias sums -> f32, zero carries -----
__global__ void prep_w(const void* __restrict__ wih0, const void* __restrict__ whh0,
                       const void* __restrict__ bih0, const void* __restrict__ bhh0,
                       const void* __restrict__ wih1, const void* __restrict__ whh1,
                       const void* __restrict__ bih1, const void* __restrict__ bhh1,
                       _Float16* __restrict__ owih0, _Float16* __restrict__ owhh0,
                       _Float16* __restrict__ owih1, _Float16* __restrict__ owhh1,
                       float* __restrict__ obias0, float* __restrict__ obias1,
                       uint4* __restrict__ carries, const int* __restrict__ flag) {
    const bool f32 = (*flag != 0);
    int i = blockIdx.x * 256 + threadIdx.x;
    auto rd = [&](const void* p, int idx) -> float {
        return f32 ? ((const float*)p)[idx] : bf2f(((const unsigned short*)p)[idx]);
    };
    if (i < H_ * D_) owih0[i] = (_Float16)rd(wih0, i);
    if (i < H_ * H_) {
        owhh0[i] = (_Float16)rd(whh0, i);
        owih1[i] = (_Float16)rd(wih1, i);
        owhh1[i] = (_Float16)rd(whh1, i);
    }
    if (i < H_) {
        obias0[i] = rd(bih0, i) + rd(bhh0, i);
        obias1[i] = rd(bih1, i) + rd(bhh1, i);
    }
    if (i < (2 * B_ * H_) / 8) carries[i] = uint4{0, 0, 0, 0};
}

// ---- projection GEMM (768 thr, 48 rows/block): out = src @ W^T + bias ----
template <int K, bool XSRC>
__device__ __forceinline__ void proj_gemm(const void* __restrict__ src,
                                          const _Float16* __restrict__ W,
                                          const float* __restrict__ bias,
                                          _Float16* __restrict__ outx,
                                          const int* __restrict__ flag,
                                          int t0, int Tc, int pb,
                                          char* __restrict__ sm, int tid) {
    constexpr int KW = K / 8;  // uint4 (8 f16) per row
    const int sg = tid >> 8, j = tid & 255;   // 3 row-subgroups x 256 cols
    const long m0 = (long)pb * 48;
    const bool f32 = XSRC && (*flag != 0);
    uint4* xt = (uint4*)sm;                   // [48][KW] (<= 24 KB)

    for (int idx = tid; idx < 48 * KW; idx += 768) {
        int r = idx / KW, c = idx % KW;
        long m = m0 + r;
        uint4 v = uint4{0, 0, 0, 0};
        if (m < (long)B_ * Tc) {
            long off;
            if (XSRC) {
                long b = m / Tc, tc = m - b * Tc;
                off = (b * T_ + t0 + tc) * (long)K + (long)c * 8;
                if (f32) {
                    const float* s = (const float*)src + off;
                    union { _Float16 h[8]; uint4 u; } r8;
#pragma unroll
                    for (int q = 0; q < 8; ++q) r8.h[q] = (_Float16)s[q];
                    v = r8.u;
                } else {
                    v = cvt8_bf16_to_f16(*(const uint4*)((const unsigned short*)src + off));
                }
            } else {
                off = m * (long)K + (long)c * 8;
                v = *(const uint4*)((const _Float16*)src + off);
            }
        }
        xt[idx] = v;
    }

    uint4 w[KW];   // W row j
    const uint4* wp = (const uint4*)(W + (long)j * K);
#pragma unroll
    for (int i = 0; i < KW; ++i) w[i] = wp[i];
    __syncthreads();

    const float bb = bias[j];
#pragma unroll 1
    for (int r = 0; r < 16; ++r) {
        const long m = m0 + sg * 16 + r;
        if (m < (long)B_ * Tc) {
            const uint4* xr = xt + (sg * 16 + r) * KW;
            float a0 = 0.f, a1 = 0.f, a2 = 0.f, a3 = 0.f;
#pragma unroll
            for (int i = 0; i < KW; ++i) {
                uint4 h = xr[i];   // wave-uniform LDS broadcast
                uint4 ww = w[i];
                a0 = dot2(ww.x, h.x, a0);
                a1 = dot2(ww.y, h.y, a1);
                a2 = dot2(ww.z, h.z, a2);
                a3 = dot2(ww.w, h.w, a3);
            }
            outx[m * H_ + j] = (_Float16)(((a0 + a1) + (a2 + a3)) + bb);
        }
    }
}

// ---- single-layer scan: h[t] = tanh(Whh h[t-1] + xw[t]) ------------------
// 512 compute threads = 8 waves; M=2 outputs/lane, K-split=4.
//   jp = wv*16+(lane&15) -> outputs j0=2jp, j0+1;  kq = lane>>4.
// h stored padded: quarter q at f16 index q*HBQ (HBQ=72 -> 144B stride);
// per-instr the 4 distinct read addresses hit disjoint bank quads.
// Waves 8-11 idle but execute the SAME barrier sequence (no exited waves).
__device__ __forceinline__ void scan_layer(const _Float16* __restrict__ xw,
                                           const _Float16* __restrict__ Whh,
                                           _Float16* __restrict__ carry,
                                           _Float16* __restrict__ hout,
                                           char* __restrict__ sm, int b,
                                           int tid, int Tc) {
    __builtin_amdgcn_s_setprio(1);                // beat co-scheduled GEMM waves
    _Float16* stage = (_Float16*)sm;              // [Tc][256] (<= 64 KB)
    _Float16* hbuf  = (_Float16*)(sm + TCMAX * H_ * 2);  // [2][4*HBQ] padded
    const bool act = (tid < 512);
    const int wv = (tid >> 6) & 7, lane = tid & 63;
    const int kq = lane >> 4;                     // K-quarter 0..3
    const int j0 = (wv * 16 + (lane & 15)) * 2;   // output pair base

    uint4 w0[8], w1[8];   // rows j0, j0+1, K-quarter kq: 64 VGPRs total
    if (act) {
        const uint4* p0 = (const uint4*)(Whh + (long)j0 * H_ + kq * 64);
        const uint4* p1 = (const uint4*)(Whh + (long)(j0 + 1) * H_ + kq * 64);
#pragma unroll
        for (int i = 0; i < 8; ++i) { w0[i] = p0[i]; w1[i] = p1[i]; }
    }

    {   // stage the whole xw chunk (all 12 waves): zero global loads in loop
        const uint4* src = (const uint4*)(xw + (long)b * Tc * H_);
        uint4* dst = (uint4*)stage;
        for (int i = tid; i < Tc * (H_ / 8); i += 768) dst[i] = src[i];
    }
    if (tid < 256) hbuf[(tid >> 6) * HBQ + (tid & 63)] = carry[b * H_ + tid];
    __syncthreads();   // full drain once (stage loads + carry init)

    unsigned hlast = 0;
#pragma unroll 1
    for (int it = 0; it < Tc; ++it) {
        const int p = it & 1;
        if (act) {
            const uint4* hb = (const uint4*)(hbuf + p * (4 * HBQ) + kq * HBQ);
            float a0 = 0.f, a1 = 0.f, b0 = 0.f, b1 = 0.f;
#pragma unroll
            for (int i = 0; i < 8; ++i) {
                uint4 h = hb[i];   // 4 distinct addrs/instr, disjoint bank quads
                a0 = dot2(w0[i].x, h.x, a0); a1 = dot2(w0[i].y, h.y, a1);
                b0 = dot2(w1[i].x, h.x, b0); b1 = dot2(w1[i].y, h.y, b1);
                a0 = dot2(w0[i].z, h.z, a0); a1 = dot2(w0[i].w, h.w, a1);
                b0 = dot2(w1[i].z, h.z, b0); b1 = dot2(w1[i].w, h.w, b1);
            }
            float s0 = a0 + a1, s1 = b0 + b1;
            s0 += __shfl_xor(s0, 16, 64); s0 += __shfl_xor(s0, 32, 64);
            s1 += __shfl_xor(s1, 16, 64); s1 += __shfl_xor(s1, 32, 64);
            union { unsigned u; _Float16 h[2]; } xh;
            xh.u = *(const unsigned*)(stage + it * H_ + j0);
            union { _Float16 h[2]; unsigned u; } pk;
            pk.h[0] = (_Float16)fast_tanh(s0 + (float)xh.h[0]);
            pk.h[1] = (_Float16)fast_tanh(s1 + (float)xh.h[1]);
            if (kq == 0) {        // state for next step (padded layout)
                *(unsigned*)(hbuf + (p ^ 1) * (4 * HBQ) + (j0 >> 6) * HBQ + (j0 & 63)) = pk.u;
            } else if (kq == 1) { // h-chunk in place of consumed xw
                *(unsigned*)(stage + it * H_ + j0) = pk.u;
            }
            hlast = pk.u;
        }
        lds_barrier();   // ALL waves, every iteration
    }

    if (act && kq == 0) *(unsigned*)(carry + (long)b * H_ + j0) = hlast;
    {   // bulk coalesced h-chunk write (all 12 waves, off the critical path)
        const uint4* src = (const uint4*)stage;
        uint4* dst = (uint4*)(hout + (long)b * Tc * H_);
        for (int i = tid; i < Tc * (H_ / 8); i += 768) dst[i] = src[i];
    }
}

// ---- transpose (768 thr): h1 [b][tc][j] f16 -> out [b][j][t0+tc] ---------
__device__ __forceinline__ void transpose_dev(const _Float16* __restrict__ tmp,
                                              void* __restrict__ out,
                                              const int* __restrict__ flag,
                                              int t0, int Tc, int pb,
                                              char* __restrict__ sm, int tid) {
    const int nTc = (Tc + 63) >> 6;
    int bid = pb;
    const int jblk = bid & 3; bid >>= 2;      // H_/64 == 4
    const int tcblk = bid % nTc;
    const int b = bid / nTc;
    const bool f32o = (*flag != 0);
    float* tile = (float*)sm;                 // [64][65]
#pragma unroll
    for (int k = 0; k < 6; ++k) {
        int idx = k * 768 + tid;
        if (idx < 4096) {
            int r = idx >> 6, c = idx & 63;
            int tc = tcblk * 64 + r;
            tile[r * 65 + c] = (tc < Tc)
                ? (float)tmp[((long)b * Tc + tc) * H_ + jblk * 64 + c] : 0.f;
        }
    }
    __syncthreads();
#pragma unroll
    for (int k = 0; k < 6; ++k) {
        int idx = k * 768 + tid;
        if (idx < 4096) {
            int jr = idx >> 6, tc = idx & 63;
            if (tcblk * 64 + tc < Tc) {
                float v = tile[tc * 65 + jr];
                long o = ((long)b * H_ + jblk * 64 + jr) * (long)T_ + t0 + tcblk * 64 + tc;
                if (f32o) ((float*)out)[o] = v;
                else      ((__hip_bfloat16*)out)[o] = __float2bfloat16(v);
            }
        }
    }
}

// ---- boot: proj0 of chunk 0 ----------------------------------------------
__global__ __launch_bounds__(768, 1) void boot(
    const void* __restrict__ x, const _Float16* __restrict__ W,
    const float* __restrict__ bias, _Float16* __restrict__ outx,
    const int* __restrict__ flag, int Tc)
{
    __shared__ __align__(16) char sm[24576];
    proj_gemm<D_, true>(x, W, bias, outx, flag, 0, Tc, blockIdx.x, sm, threadIdx.x);
}

// ---- mega: scan0(d) || scan1(d-2) || proj0(d+1) || proj1(d-1) || tr(d-3) -
__global__ __launch_bounds__(768, 1) void mega(
    const void* __restrict__ x,
    const _Float16* __restrict__ Wih0, const _Float16* __restrict__ Whh0,
    const _Float16* __restrict__ Wih1, const _Float16* __restrict__ Whh1,
    const float* __restrict__ bias0, const float* __restrict__ bias1,
    _Float16* __restrict__ carry0, _Float16* __restrict__ carry1,
    const _Float16* __restrict__ xw0r, _Float16* __restrict__ xw0w,
    _Float16* __restrict__ h0w, const _Float16* __restrict__ h0r,
    _Float16* __restrict__ xw1w, const _Float16* __restrict__ xw1r,
    _Float16* __restrict__ h1w, const _Float16* __restrict__ h1r,
    void* __restrict__ dout, const int* __restrict__ flag,
    int v_s0, int t_p0, int v_p1, int v_s1, int t_tr, int Tc, int nproj)
{
    __shared__ __align__(16) char sm[TCMAX * H_ * 2 + 2048];  // 67584 B
    const int bid = blockIdx.x;
    const int tid = threadIdx.x;

    if (bid < 64) {                              // scan0 chunk d
        if (!v_s0) return;
        scan_layer(xw0r, Whh0, carry0, h0w, sm, bid, tid, Tc);
    } else if (bid < 128) {                      // scan1 chunk d-2
        if (!v_s1) return;
        scan_layer(xw1r, Whh1, carry1, h1w, sm, bid - 64, tid, Tc);
    } else if (bid < 128 + nproj) {              // proj0 chunk d+1
        if (t_p0 < 0) return;
        proj_gemm<D_, true>(x, Wih0, bias0, xw0w, flag, t_p0, Tc, bid - 128, sm, tid);
    } else if (bid < 128 + 2 * nproj) {          // proj1 chunk d-1
        if (!v_p1) return;
        proj_gemm<H_, false>(h0r, Wih1, bias1, xw1w, flag, 0, Tc, bid - 128 - nproj, sm, tid);
    } else {                                     // transpose chunk d-3
        if (t_tr < 0) return;
        transpose_dev(h1r, dout, flag, t_tr, Tc, bid - 128 - 2 * nproj, sm, tid);
    }
}

// ---------------------------------------------------------------------------
extern "C" void kernel_launch(void* const* d_in, const int* in_sizes, int n_in,
                              void* d_out, int out_size, void* d_ws, size_t ws_size,
                              hipStream_t stream) {
    const void* x    = d_in[0];
    const void* wih0 = d_in[1];
    const void* whh0 = d_in[2];
    const void* bih0 = d_in[3];
    const void* bhh0 = d_in[4];
    const void* wih1 = d_in[5];
    const void* whh1 = d_in[6];
    const void* bih1 = d_in[7];
    const void* bhh1 = d_in[8];
    (void)in_sizes; (void)n_in; (void)out_size;

    char* ws = (char*)d_ws;
    size_t off = 0;
    auto alloc = [&](size_t bytes) -> void* {
        void* p = ws + off;
        off += (bytes + 255) & ~(size_t)255;
        return p;
    };

    int*      flag    = (int*)alloc(256);
    _Float16* wih0_16 = (_Float16*)alloc((size_t)H_ * D_ * 2);
    _Float16* whh0_16 = (_Float16*)alloc((size_t)H_ * H_ * 2);
    _Float16* wih1_16 = (_Float16*)alloc((size_t)H_ * H_ * 2);
    _Float16* whh1_16 = (_Float16*)alloc((size_t)H_ * H_ * 2);
    float*    bias0   = (float*)alloc(H_ * 4);
    float*    bias1   = (float*)alloc(H_ * 4);
    _Float16* carry0  = (_Float16*)alloc((size_t)B_ * H_ * 2);   // must stay
    _Float16* carry1  = (_Float16*)alloc((size_t)B_ * H_ * 2);   // adjacent

    size_t fixed = off;
    // largest Tc (<=TCMAX) whose EIGHT chunk buffers fit in ws
    int Tc = TCMAX;
    while (Tc > 32 && fixed + 8 * ((size_t)B_ * Tc * H_ * 2 + 256) > ws_size) Tc >>= 1;
    _Float16 *xw0g[2], *xw1g[2], *h0g[2], *h1g[2];
    for (int i = 0; i < 2; ++i) xw0g[i] = (_Float16*)alloc((size_t)B_ * Tc * H_ * 2);
    for (int i = 0; i < 2; ++i) xw1g[i] = (_Float16*)alloc((size_t)B_ * Tc * H_ * 2);
    for (int i = 0; i < 2; ++i) h0g[i]  = (_Float16*)alloc((size_t)B_ * Tc * H_ * 2);
    for (int i = 0; i < 2; ++i) h1g[i]  = (_Float16*)alloc((size_t)B_ * Tc * H_ * 2);

    detect_dtype<<<1, 64, 0, stream>>>((const unsigned short*)whh0, flag);
    prep_w<<<(H_ * H_ + 255) / 256, 256, 0, stream>>>(
        wih0, whh0, bih0, bhh0, wih1, whh1, bih1, bhh1,
        wih0_16, whh0_16, wih1_16, whh1_16, bias0, bias1, (uint4*)carry0, flag);

    const int NC     = T_ / Tc;
    const int nproj  = (B_ * Tc + 47) / 48;
    const int ntrans = B_ * ((Tc + 63) / 64) * (H_ / 64);
    const int grid   = 128 + 2 * nproj + ntrans;

    boot<<<nproj, 768, 0, stream>>>(x, wih0_16, bias0, xw0g[0], flag, Tc);

    for (int d = 0; d <= NC + 2; ++d) {
        const int v_s0 = (d < NC) ? 1 : 0;                       // scan0 chunk d
        const int t_p0 = (d + 1 < NC) ? (d + 1) * Tc : -1;       // proj0 chunk d+1
        const int v_p1 = (d - 1 >= 0 && d - 1 < NC) ? 1 : 0;     // proj1 chunk d-1
        const int v_s1 = (d - 2 >= 0 && d - 2 < NC) ? 1 : 0;     // scan1 chunk d-2
        const int t_tr = (d - 3 >= 0 && d - 3 < NC) ? (d - 3) * Tc : -1;
        mega<<<grid, 768, 0, stream>>>(
            x, wih0_16, whh0_16, wih1_16, whh1_16, bias0, bias1,
            carry0, carry1,
            xw0g[d & 1],            // scan0 reads chunk d
            xw0g[(d + 1) & 1],      // proj0 writes chunk d+1
            h0g[d & 1],             // scan0 writes chunk d
            h0g[(d - 1) & 1],       // proj1 reads chunk d-1
            xw1g[(d - 1) & 1],      // proj1 writes chunk d-1
            xw1g[(d - 2) & 1],      // scan1 reads chunk d-2
            h1g[(d - 2) & 1],       // scan1 writes chunk d-2
            h1g[(d - 3) & 1],       // transpose reads chunk d-3
            d_out, flag, v_s0, t_p0, v_p1, v_s1, t_tr, Tc, nproj);
    }
}

// Round 11
// 888.912 us; speedup vs baseline: 1.0588x; 1.0588x over previous
//
#include <hip/hip_runtime.h>
#include <hip/hip_bf16.h>

// ---------------------------------------------------------------------------
// RNN_20572893348005: 2-layer tanh RNN, B=64 T=1024 D=128 H=256, out [B,H,T]
//
// v12 = v10 (best measured: 872 us, scan dispatch 86 us) + CU exclusivity
// restored. v11 falsified the LDS-bandwidth theory (halving h-read traffic
// left the step at ~1700 cy); the remaining model term for the 3x gap vs the
// ~520 cy latency chain is CO-SCHEDULING: at 67.5 KB LDS, 2 blocks/CU fit,
// so GEMM blocks co-reside on scan CUs (the measured v7 regression,
// re-introduced in v9-v11). Single change: pad mega's static LDS to 82432 B
// (> 160KiB/2; the exact v8-proven constant) -> 1 block/CU. Scan blocks
// 0-127 dispatch first and claim dedicated CUs; ~850 GEMM/transpose blocks
// cycle on the remaining CUs, hidden under the scan.
//   blocks 0-63   : scan0 chunk d      (512 compute thr: 1 output/lane,
//   blocks 64-127 : scan1 chunk d-2     2-way K-split, 64 weight VGPRs)
//   blocks 128+   : proj0(d+1) GEMM, proj1(d-1) GEMM, transpose(d-3)
// Scan step: 16 broadcast ds_read_b128 (2-addr = free), 64 dot2 (4 chains),
// 1 shfl_xor(32), tanh; h-chunk overwrites consumed xw slot in LDS stage
// (zero per-step global stores; bulk coalesced copy at end); raw
// lgkmcnt-only barrier; ALL waves alive through the barrier loop (v9 lesson).
// ---------------------------------------------------------------------------

#define B_ 64
#define T_ 1024
#define D_ 128
#define H_ 256
#define TCMAX 128              // LDS stage = TCMAX*H*2 = 64 KB
#define SMEM_BYTES 82432       // > 81920 forces 1 block/CU (v8-proven constant)

typedef _Float16 half2_t __attribute__((ext_vector_type(2)));

__device__ __forceinline__ float bf2f(unsigned short u) {
    union { unsigned int i; float f; } v;
    v.i = ((unsigned int)u) << 16;
    return v.f;
}

__device__ __forceinline__ unsigned int cvt2_bf16_to_f16(unsigned int u) {
    union { float f; unsigned int i; } a, b;
    a.i = u << 16;
    b.i = u & 0xFFFF0000u;
    union { _Float16 h[2]; unsigned int u; } r;
    r.h[0] = (_Float16)a.f;
    r.h[1] = (_Float16)b.f;
    return r.u;
}

__device__ __forceinline__ uint4 cvt8_bf16_to_f16(uint4 v) {
    uint4 r;
    r.x = cvt2_bf16_to_f16(v.x);
    r.y = cvt2_bf16_to_f16(v.y);
    r.z = cvt2_bf16_to_f16(v.z);
    r.w = cvt2_bf16_to_f16(v.w);
    return r;
}

__device__ __forceinline__ float dot2(unsigned int a, unsigned int b, float c) {
    union { unsigned int u; half2_t h; } ua, ub;
    ua.u = a; ub.u = b;
#if defined(__HIP_DEVICE_COMPILE__) && __has_builtin(__builtin_amdgcn_fdot2)
    return __builtin_amdgcn_fdot2(ua.h, ub.h, c, false);
#else
    return c + (float)ua.h.x * (float)ub.h.x + (float)ua.h.y * (float)ub.h.y;
#endif
}

// branch-free tanh: (e^{2x}-1)/(e^{2x}+1) via exp2 + rcp; saturates correctly.
__device__ __forceinline__ float fast_tanh(float x) {
#if defined(__HIP_DEVICE_COMPILE__) && __has_builtin(__builtin_amdgcn_exp2f)
    float e = __builtin_amdgcn_exp2f(x * 2.885390081777927f);
#else
    float e = __expf(2.0f * x);
#endif
#if defined(__HIP_DEVICE_COMPILE__) && __has_builtin(__builtin_amdgcn_rcpf)
    return 1.0f - 2.0f * __builtin_amdgcn_rcpf(e + 1.0f);
#else
    return 1.0f - 2.0f / (e + 1.0f);
#endif
}

// raw workgroup barrier: LDS ordering only (no vmcnt drain). v6-v10-proven.
// Executed by ALL waves of the block (no exited waves - the v9 hazard).
__device__ __forceinline__ void lds_barrier() {
    asm volatile("s_waitcnt lgkmcnt(0)\n\ts_barrier" ::: "memory");
}

// ---- dtype detection ------------------------------------------------------
__global__ void detect_dtype(const unsigned short* __restrict__ w, int* __restrict__ flag) {
    if (threadIdx.x == 0 && blockIdx.x == 0) {
        int f = 0;
        for (int i = 0; i < 512; ++i) {
            unsigned e = (w[i] >> 7) & 0xFF;
            if (e >= 127) f = 1;
        }
        *flag = f;
    }
}

// ---- prep: weights (bf16|f32) -> f16, bias sums -> f32, zero carries -----
__global__ void prep_w(const void* __restrict__ wih0, const void* __restrict__ whh0,
                       const void* __restrict__ bih0, const void* __restrict__ bhh0,
                       const void* __restrict__ wih1, const void* __restrict__ whh1,
                       const void* __restrict__ bih1, const void* __restrict__ bhh1,
                       _Float16* __restrict__ owih0, _Float16* __restrict__ owhh0,
                       _Float16* __restrict__ owih1, _Float16* __restrict__ owhh1,
                       float* __restrict__ obias0, float* __restrict__ obias1,
                       uint4* __restrict__ carries, const int* __restrict__ flag) {
    const bool f32 = (*flag != 0);
    int i = blockIdx.x * 256 + threadIdx.x;
    auto rd = [&](const void* p, int idx) -> float {
        return f32 ? ((const float*)p)[idx] : bf2f(((const unsigned short*)p)[idx]);
    };
    if (i < H_ * D_) owih0[i] = (_Float16)rd(wih0, i);
    if (i < H_ * H_) {
        owhh0[i] = (_Float16)rd(whh0, i);
        owih1[i] = (_Float16)rd(wih1, i);
        owhh1[i] = (_Float16)rd(whh1, i);
    }
    if (i < H_) {
        obias0[i] = rd(bih0, i) + rd(bhh0, i);
        obias1[i] = rd(bih1, i) + rd(bhh1, i);
    }
    if (i < (2 * B_ * H_) / 8) carries[i] = uint4{0, 0, 0, 0};
}

// ---- projection GEMM (768 thr, 48 rows/block): out = src @ W^T + bias ----
template <int K, bool XSRC>
__device__ __forceinline__ void proj_gemm(const void* __restrict__ src,
                                          const _Float16* __restrict__ W,
                                          const float* __restrict__ bias,
                                          _Float16* __restrict__ outx,
                                          const int* __restrict__ flag,
                                          int t0, int Tc, int pb,
                                          char* __restrict__ sm, int tid) {
    constexpr int KW = K / 8;  // uint4 (8 f16) per row
    const int sg = tid >> 8, j = tid & 255;   // 3 row-subgroups x 256 cols
    const long m0 = (long)pb * 48;
    const bool f32 = XSRC && (*flag != 0);
    uint4* xt = (uint4*)sm;                   // [48][KW] (<= 24 KB)

    for (int idx = tid; idx < 48 * KW; idx += 768) {
        int r = idx / KW, c = idx % KW;
        long m = m0 + r;
        uint4 v = uint4{0, 0, 0, 0};
        if (m < (long)B_ * Tc) {
            long off;
            if (XSRC) {
                long b = m / Tc, tc = m - b * Tc;
                off = (b * T_ + t0 + tc) * (long)K + (long)c * 8;
                if (f32) {
                    const float* s = (const float*)src + off;
                    union { _Float16 h[8]; uint4 u; } r8;
#pragma unroll
                    for (int q = 0; q < 8; ++q) r8.h[q] = (_Float16)s[q];
                    v = r8.u;
                } else {
                    v = cvt8_bf16_to_f16(*(const uint4*)((const unsigned short*)src + off));
                }
            } else {
                off = m * (long)K + (long)c * 8;
                v = *(const uint4*)((const _Float16*)src + off);
            }
        }
        xt[idx] = v;
    }

    uint4 w[KW];   // W row j
    const uint4* wp = (const uint4*)(W + (long)j * K);
#pragma unroll
    for (int i = 0; i < KW; ++i) w[i] = wp[i];
    __syncthreads();

    const float bb = bias[j];
#pragma unroll 1
    for (int r = 0; r < 16; ++r) {
        const long m = m0 + sg * 16 + r;
        if (m < (long)B_ * Tc) {
            const uint4* xr = xt + (sg * 16 + r) * KW;
            float a0 = 0.f, a1 = 0.f, a2 = 0.f, a3 = 0.f;
#pragma unroll
            for (int i = 0; i < KW; ++i) {
                uint4 h = xr[i];   // wave-uniform LDS broadcast
                uint4 ww = w[i];
                a0 = dot2(ww.x, h.x, a0);
                a1 = dot2(ww.y, h.y, a1);
                a2 = dot2(ww.z, h.z, a2);
                a3 = dot2(ww.w, h.w, a3);
            }
            outx[m * H_ + j] = (_Float16)(((a0 + a1) + (a2 + a3)) + bb);
        }
    }
}

// ---- single-layer scan: h[t] = tanh(Whh h[t-1] + xw[t]) ------------------
// 512 compute threads = 8 waves; lane -> output jj = wv*32+(lane&31),
// K-half = lane>>5. Weights = 128 f16 = 64 VGPRs (arch-resident regime).
// Waves 8-11 idle but execute the SAME barrier sequence (no exited waves).
// h-chunk overwrites consumed xw slot in the LDS stage (half==1 lane);
// bulk coalesced global copy after the loop.
__device__ __forceinline__ void scan_layer(const _Float16* __restrict__ xw,
                                           const _Float16* __restrict__ Whh,
                                           _Float16* __restrict__ carry,
                                           _Float16* __restrict__ hout,
                                           char* __restrict__ sm, int b,
                                           int tid, int Tc) {
    __builtin_amdgcn_s_setprio(1);                // scan waves win VALU arbitration
    _Float16* stage = (_Float16*)sm;              // [Tc][256] (<= 64 KB)
    _Float16* hbuf  = (_Float16*)(sm + TCMAX * H_ * 2);  // [2][256]
    const bool act = (tid < 512);
    const int wv = tid >> 6, lane = tid & 63, half = lane >> 5;
    const int jj = (wv & 7) * 32 + (lane & 31);

    uint4 w[16];   // 128 f16: row jj, K-half (loaded by compute threads only)
    if (act) {
        const uint4* wp = (const uint4*)(Whh + (long)jj * H_ + half * 128);
#pragma unroll
        for (int i = 0; i < 16; ++i) w[i] = wp[i];
    }

    {   // stage the whole xw chunk (all 12 waves): zero global loads in loop
        const uint4* src = (const uint4*)(xw + (long)b * Tc * H_);
        uint4* dst = (uint4*)stage;
        for (int i = tid; i < Tc * (H_ / 8); i += 768) dst[i] = src[i];
    }
    if (tid < 256) hbuf[tid] = carry[b * H_ + tid];
    __syncthreads();   // full drain once (stage loads + carry init)

    float hlast = 0.f;
#pragma unroll 1
    for (int it = 0; it < Tc; ++it) {
        const int p = it & 1;
        if (act) {
            float xh = (float)stage[it * H_ + jj];     // broadcast pair read
            const uint4* hb = (const uint4*)(hbuf + p * H_) + half * 16;
            float a0 = 0.f, a1 = 0.f, a2 = 0.f, a3 = 0.f;
#pragma unroll
            for (int i = 0; i < 16; ++i) {
                uint4 h = hb[i];   // 2-addr broadcast read: conflict-free
                uint4 ww = w[i];
                a0 = dot2(ww.x, h.x, a0);
                a1 = dot2(ww.y, h.y, a1);
                a2 = dot2(ww.z, h.z, a2);
                a3 = dot2(ww.w, h.w, a3);
            }
            float s = (a0 + a1) + (a2 + a3);
            s += __shfl_xor(s, 32, 64);
            float hv = fast_tanh(s + xh);
            _Float16 hf = (_Float16)hv;
            if (half == 0) hbuf[(p ^ 1) * H_ + jj] = hf;  // state for next step
            else           stage[it * H_ + jj]     = hf;  // h in place of xw
            hlast = hv;
        }
        lds_barrier();   // ALL waves, every iteration
    }

    if (act && half == 0) carry[b * H_ + jj] = (_Float16)hlast;
    {   // bulk coalesced h-chunk write (all 12 waves, off the critical path)
        const uint4* src = (const uint4*)stage;
        uint4* dst = (uint4*)(hout + (long)b * Tc * H_);
        for (int i = tid; i < Tc * (H_ / 8); i += 768) dst[i] = src[i];
    }
}

// ---- transpose (768 thr): h1 [b][tc][j] f16 -> out [b][j][t0+tc] ---------
__device__ __forceinline__ void transpose_dev(const _Float16* __restrict__ tmp,
                                              void* __restrict__ out,
                                              const int* __restrict__ flag,
                                              int t0, int Tc, int pb,
                                              char* __restrict__ sm, int tid) {
    const int nTc = (Tc + 63) >> 6;
    int bid = pb;
    const int jblk = bid & 3; bid >>= 2;      // H_/64 == 4
    const int tcblk = bid % nTc;
    const int b = bid / nTc;
    const bool f32o = (*flag != 0);
    float* tile = (float*)sm;                 // [64][65]
#pragma unroll
    for (int k = 0; k < 6; ++k) {
        int idx = k * 768 + tid;
        if (idx < 4096) {
            int r = idx >> 6, c = idx & 63;
            int tc = tcblk * 64 + r;
            tile[r * 65 + c] = (tc < Tc)
                ? (float)tmp[((long)b * Tc + tc) * H_ + jblk * 64 + c] : 0.f;
        }
    }
    __syncthreads();
#pragma unroll
    for (int k = 0; k < 6; ++k) {
        int idx = k * 768 + tid;
        if (idx < 4096) {
            int jr = idx >> 6, tc = idx & 63;
            if (tcblk * 64 + tc < Tc) {
                float v = tile[tc * 65 + jr];
                long o = ((long)b * H_ + jblk * 64 + jr) * (long)T_ + t0 + tcblk * 64 + tc;
                if (f32o) ((float*)out)[o] = v;
                else      ((__hip_bfloat16*)out)[o] = __float2bfloat16(v);
            }
        }
    }
}

// ---- boot: proj0 of chunk 0 ----------------------------------------------
__global__ __launch_bounds__(768, 1) void boot(
    const void* __restrict__ x, const _Float16* __restrict__ W,
    const float* __restrict__ bias, _Float16* __restrict__ outx,
    const int* __restrict__ flag, int Tc)
{
    __shared__ __align__(16) char sm[24576];
    proj_gemm<D_, true>(x, W, bias, outx, flag, 0, Tc, blockIdx.x, sm, threadIdx.x);
}

// ---- mega: scan0(d) || scan1(d-2) || proj0(d+1) || proj1(d-1) || tr(d-3) -
__global__ __launch_bounds__(768, 1) void mega(
    const void* __restrict__ x,
    const _Float16* __restrict__ Wih0, const _Float16* __restrict__ Whh0,
    const _Float16* __restrict__ Wih1, const _Float16* __restrict__ Whh1,
    const float* __restrict__ bias0, const float* __restrict__ bias1,
    _Float16* __restrict__ carry0, _Float16* __restrict__ carry1,
    const _Float16* __restrict__ xw0r, _Float16* __restrict__ xw0w,
    _Float16* __restrict__ h0w, const _Float16* __restrict__ h0r,
    _Float16* __restrict__ xw1w, const _Float16* __restrict__ xw1r,
    _Float16* __restrict__ h1w, const _Float16* __restrict__ h1r,
    void* __restrict__ dout, const int* __restrict__ flag,
    int v_s0, int t_p0, int v_p1, int v_s1, int t_tr, int Tc, int nproj)
{
    // > 80 KiB: 1 block/CU. GEMM/transpose blocks can never co-schedule onto
    // the latency-critical scan CUs (v7-measured regression; v8-proven fix).
    __shared__ __align__(16) char sm[SMEM_BYTES];
    const int bid = blockIdx.x;
    const int tid = threadIdx.x;

    if (bid < 64) {                              // scan0 chunk d
        if (!v_s0) return;
        scan_layer(xw0r, Whh0, carry0, h0w, sm, bid, tid, Tc);
    } else if (bid < 128) {                      // scan1 chunk d-2
        if (!v_s1) return;
        scan_layer(xw1r, Whh1, carry1, h1w, sm, bid - 64, tid, Tc);
    } else if (bid < 128 + nproj) {              // proj0 chunk d+1
        if (t_p0 < 0) return;
        proj_gemm<D_, true>(x, Wih0, bias0, xw0w, flag, t_p0, Tc, bid - 128, sm, tid);
    } else if (bid < 128 + 2 * nproj) {          // proj1 chunk d-1
        if (!v_p1) return;
        proj_gemm<H_, false>(h0r, Wih1, bias1, xw1w, flag, 0, Tc, bid - 128 - nproj, sm, tid);
    } else {                                     // transpose chunk d-3
        if (t_tr < 0) return;
        transpose_dev(h1r, dout, flag, t_tr, Tc, bid - 128 - 2 * nproj, sm, tid);
    }
}

// ---------------------------------------------------------------------------
extern "C" void kernel_launch(void* const* d_in, const int* in_sizes, int n_in,
                              void* d_out, int out_size, void* d_ws, size_t ws_size,
                              hipStream_t stream) {
    const void* x    = d_in[0];
    const void* wih0 = d_in[1];
    const void* whh0 = d_in[2];
    const void* bih0 = d_in[3];
    const void* bhh0 = d_in[4];
    const void* wih1 = d_in[5];
    const void* whh1 = d_in[6];
    const void* bih1 = d_in[7];
    const void* bhh1 = d_in[8];
    (void)in_sizes; (void)n_in; (void)out_size;

    char* ws = (char*)d_ws;
    size_t off = 0;
    auto alloc = [&](size_t bytes) -> void* {
        void* p = ws + off;
        off += (bytes + 255) & ~(size_t)255;
        return p;
    };

    int*      flag    = (int*)alloc(256);
    _Float16* wih0_16 = (_Float16*)alloc((size_t)H_ * D_ * 2);
    _Float16* whh0_16 = (_Float16*)alloc((size_t)H_ * H_ * 2);
    _Float16* wih1_16 = (_Float16*)alloc((size_t)H_ * H_ * 2);
    _Float16* whh1_16 = (_Float16*)alloc((size_t)H_ * H_ * 2);
    float*    bias0   = (float*)alloc(H_ * 4);
    float*    bias1   = (float*)alloc(H_ * 4);
    _Float16* carry0  = (_Float16*)alloc((size_t)B_ * H_ * 2);   // must stay
    _Float16* carry1  = (_Float16*)alloc((size_t)B_ * H_ * 2);   // adjacent

    size_t fixed = off;
    // largest Tc (<=TCMAX) whose EIGHT chunk buffers fit in ws
    int Tc = TCMAX;
    while (Tc > 32 && fixed + 8 * ((size_t)B_ * Tc * H_ * 2 + 256) > ws_size) Tc >>= 1;
    _Float16 *xw0g[2], *xw1g[2], *h0g[2], *h1g[2];
    for (int i = 0; i < 2; ++i) xw0g[i] = (_Float16*)alloc((size_t)B_ * Tc * H_ * 2);
    for (int i = 0; i < 2; ++i) xw1g[i] = (_Float16*)alloc((size_t)B_ * Tc * H_ * 2);
    for (int i = 0; i < 2; ++i) h0g[i]  = (_Float16*)alloc((size_t)B_ * Tc * H_ * 2);
    for (int i = 0; i < 2; ++i) h1g[i]  = (_Float16*)alloc((size_t)B_ * Tc * H_ * 2);

    detect_dtype<<<1, 64, 0, stream>>>((const unsigned short*)whh0, flag);
    prep_w<<<(H_ * H_ + 255) / 256, 256, 0, stream>>>(
        wih0, whh0, bih0, bhh0, wih1, whh1, bih1, bhh1,
        wih0_16, whh0_16, wih1_16, whh1_16, bias0, bias1, (uint4*)carry0, flag);

    const int NC     = T_ / Tc;
    const int nproj  = (B_ * Tc + 47) / 48;
    const int ntrans = B_ * ((Tc + 63) / 64) * (H_ / 64);
    const int grid   = 128 + 2 * nproj + ntrans;

    boot<<<nproj, 768, 0, stream>>>(x, wih0_16, bias0, xw0g[0], flag, Tc);

    for (int d = 0; d <= NC + 2; ++d) {
        const int v_s0 = (d < NC) ? 1 : 0;                       // scan0 chunk d
        const int t_p0 = (d + 1 < NC) ? (d + 1) * Tc : -1;       // proj0 chunk d+1
        const int v_p1 = (d - 1 >= 0 && d - 1 < NC) ? 1 : 0;     // proj1 chunk d-1
        const int v_s1 = (d - 2 >= 0 && d - 2 < NC) ? 1 : 0;     // scan1 chunk d-2
        const int t_tr = (d - 3 >= 0 && d - 3 < NC) ? (d - 3) * Tc : -1;
        mega<<<grid, 768, 0, stream>>>(
            x, wih0_16, whh0_16, wih1_16, whh1_16, bias0, bias1,
            carry0, carry1,
            xw0g[d & 1],            // scan0 reads chunk d
            xw0g[(d + 1) & 1],      // proj0 writes chunk d+1
            h0g[d & 1],             // scan0 writes chunk d
            h0g[(d - 1) & 1],       // proj1 reads chunk d-1
            xw1g[(d - 1) & 1],      // proj1 writes chunk d-1
            xw1g[(d - 2) & 1],      // scan1 reads chunk d-2
            h1g[(d - 2) & 1],       // scan1 writes chunk d-2
            h1g[(d - 3) & 1],       // transpose reads chunk d-3
            d_out, flag, v_s0, t_p0, v_p1, v_s1, t_tr, Tc, nproj);
    }
}

// Round 12
// 843.414 us; speedup vs baseline: 1.1159x; 1.0539x over previous
//
#include <hip/hip_runtime.h>
#include <hip/hip_bf16.h>

// ---------------------------------------------------------------------------
// RNN_20572893348005: 2-layer tanh RNN, B=64 T=1024 D=128 H=256, out [B,H,T]
//
// v13 = v12 with three latency-chain cuts (v11/v12 falsified the traffic and
// co-scheduling theories; the step is a serial LDS-latency + barrier chain):
//  (1) __shfl_xor(32) [ds-pipe, ~90-120cy] -> v_permlane32_swap_b32 [VALU]
//      + cndmask for the cross-half partial: one LDS hop removed.
//  (2) 512-thread blocks (8 waves, ALL compute, all alive through barriers);
//      fewer barrier participants than v12's 12 waves (4 idle).
//  (3) Tc=64: scan wall = T+3*Tc = 1216 steps (was 1408, -14%); GEMM rounds
//      (~16us on the 128 free CUs) still hide under the 64-step scan.
// Roles per dispatch d (deps span dispatch boundaries, v6-proven):
//   blocks 0-63   : scan0 chunk d      (8 waves x 32 outputs, 2-way K-split,
//   blocks 64-127 : scan1 chunk d-2     64 weight VGPRs, arch-resident)
//   blocks 128+   : proj0(d+1) GEMM, proj1(d-1) GEMM, transpose(d-3)
// Scan step: 16 broadcast ds_read_b128 + xh read, 64 dot2 (4 chains),
// permlane32 half-exchange, tanh, LDS h-write; raw lgkmcnt-only barrier;
// LDS stage with in-place h overwrite; bulk coalesced copies; exclusivity
// pad 82432 B (1 block/CU) kept.
// ---------------------------------------------------------------------------

#define B_ 64
#define T_ 1024
#define D_ 128
#define H_ 256
#define TCMAX 64               // LDS stage = TCMAX*H*2 = 32 KB
#define SMEM_BYTES 82432       // > 81920 forces 1 block/CU (v8-proven constant)

typedef _Float16 half2_t __attribute__((ext_vector_type(2)));

__device__ __forceinline__ float bf2f(unsigned short u) {
    union { unsigned int i; float f; } v;
    v.i = ((unsigned int)u) << 16;
    return v.f;
}

__device__ __forceinline__ unsigned int cvt2_bf16_to_f16(unsigned int u) {
    union { float f; unsigned int i; } a, b;
    a.i = u << 16;
    b.i = u & 0xFFFF0000u;
    union { _Float16 h[2]; unsigned int u; } r;
    r.h[0] = (_Float16)a.f;
    r.h[1] = (_Float16)b.f;
    return r.u;
}

__device__ __forceinline__ uint4 cvt8_bf16_to_f16(uint4 v) {
    uint4 r;
    r.x = cvt2_bf16_to_f16(v.x);
    r.y = cvt2_bf16_to_f16(v.y);
    r.z = cvt2_bf16_to_f16(v.z);
    r.w = cvt2_bf16_to_f16(v.w);
    return r;
}

__device__ __forceinline__ float dot2(unsigned int a, unsigned int b, float c) {
    union { unsigned int u; half2_t h; } ua, ub;
    ua.u = a; ub.u = b;
#if defined(__HIP_DEVICE_COMPILE__) && __has_builtin(__builtin_amdgcn_fdot2)
    return __builtin_amdgcn_fdot2(ua.h, ub.h, c, false);
#else
    return c + (float)ua.h.x * (float)ub.h.x + (float)ua.h.y * (float)ub.h.y;
#endif
}

// branch-free tanh: (e^{2x}-1)/(e^{2x}+1) via exp2 + rcp; saturates correctly.
__device__ __forceinline__ float fast_tanh(float x) {
#if defined(__HIP_DEVICE_COMPILE__) && __has_builtin(__builtin_amdgcn_exp2f)
    float e = __builtin_amdgcn_exp2f(x * 2.885390081777927f);
#else
    float e = __expf(2.0f * x);
#endif
#if defined(__HIP_DEVICE_COMPILE__) && __has_builtin(__builtin_amdgcn_rcpf)
    return 1.0f - 2.0f * __builtin_amdgcn_rcpf(e + 1.0f);
#else
    return 1.0f - 2.0f / (e + 1.0f);
#endif
}

// raw workgroup barrier: LDS ordering only (no vmcnt drain). v6-v12-proven.
__device__ __forceinline__ void lds_barrier() {
    asm volatile("s_waitcnt lgkmcnt(0)\n\ts_barrier" ::: "memory");
}

// cross-half (lane ^ 32) partner via VALU permlane32_swap (no LDS pipe).
// With x=y=s: x' = {s.lo, s.lo}, y' = {s.hi, s.hi} -> partner is
// (lane<32) ? y' : x'. s_nops guard producer/consumer wait states.
__device__ __forceinline__ float half_partner(float s, int lane) {
    float x = s, y = s;
    asm volatile("s_nop 1\n\tv_permlane32_swap_b32 %0, %1\n\ts_nop 1"
                 : "+v"(x), "+v"(y));
    return (lane < 32) ? y : x;
}

// ---- dtype detection ------------------------------------------------------
__global__ void detect_dtype(const unsigned short* __restrict__ w, int* __restrict__ flag) {
    if (threadIdx.x == 0 && blockIdx.x == 0) {
        int f = 0;
        for (int i = 0; i < 512; ++i) {
            unsigned e = (w[i] >> 7) & 0xFF;
            if (e >= 127) f = 1;
        }
        *flag = f;
    }
}

// ---- prep: weights (bf16|f32) -> f16, bias sums -> f32, zero carries -----
__global__ void prep_w(const void* __restrict__ wih0, const void* __restrict__ whh0,
                       const void* __restrict__ bih0, const void* __restrict__ bhh0,
                       const void* __restrict__ wih1, const void* __restrict__ whh1,
                       const void* __restrict__ bih1, const void* __restrict__ bhh1,
                       _Float16* __restrict__ owih0, _Float16* __restrict__ owhh0,
                       _Float16* __restrict__ owih1, _Float16* __restrict__ owhh1,
                       float* __restrict__ obias0, float* __restrict__ obias1,
                       uint4* __restrict__ carries, const int* __restrict__ flag) {
    const bool f32 = (*flag != 0);
    int i = blockIdx.x * 256 + threadIdx.x;
    auto rd = [&](const void* p, int idx) -> float {
        return f32 ? ((const float*)p)[idx] : bf2f(((const unsigned short*)p)[idx]);
    };
    if (i < H_ * D_) owih0[i] = (_Float16)rd(wih0, i);
    if (i < H_ * H_) {
        owhh0[i] = (_Float16)rd(whh0, i);
        owih1[i] = (_Float16)rd(wih1, i);
        owhh1[i] = (_Float16)rd(whh1, i);
    }
    if (i < H_) {
        obias0[i] = rd(bih0, i) + rd(bhh0, i);
        obias1[i] = rd(bih1, i) + rd(bhh1, i);
    }
    if (i < (2 * B_ * H_) / 8) carries[i] = uint4{0, 0, 0, 0};
}

// ---- projection GEMM (512 thr, 32 rows/block): out = src @ W^T + bias ----
template <int K, bool XSRC>
__device__ __forceinline__ void proj_gemm(const void* __restrict__ src,
                                          const _Float16* __restrict__ W,
                                          const float* __restrict__ bias,
                                          _Float16* __restrict__ outx,
                                          const int* __restrict__ flag,
                                          int t0, int Tc, int pb,
                                          char* __restrict__ sm, int tid) {
    constexpr int KW = K / 8;  // uint4 (8 f16) per row
    const int sg = tid >> 8, j = tid & 255;   // 2 row-subgroups x 256 cols
    const long m0 = (long)pb * 32;
    const bool f32 = XSRC && (*flag != 0);
    uint4* xt = (uint4*)sm;                   // [32][KW] (<= 16 KB)

    for (int idx = tid; idx < 32 * KW; idx += 512) {
        int r = idx / KW, c = idx % KW;
        long m = m0 + r;
        uint4 v = uint4{0, 0, 0, 0};
        if (m < (long)B_ * Tc) {
            long off;
            if (XSRC) {
                long b = m / Tc, tc = m - b * Tc;
                off = (b * T_ + t0 + tc) * (long)K + (long)c * 8;
                if (f32) {
                    const float* s = (const float*)src + off;
                    union { _Float16 h[8]; uint4 u; } r8;
#pragma unroll
                    for (int q = 0; q < 8; ++q) r8.h[q] = (_Float16)s[q];
                    v = r8.u;
                } else {
                    v = cvt8_bf16_to_f16(*(const uint4*)((const unsigned short*)src + off));
                }
            } else {
                off = m * (long)K + (long)c * 8;
                v = *(const uint4*)((const _Float16*)src + off);
            }
        }
        xt[idx] = v;
    }

    uint4 w[KW];   // W row j
    const uint4* wp = (const uint4*)(W + (long)j * K);
#pragma unroll
    for (int i = 0; i < KW; ++i) w[i] = wp[i];
    __syncthreads();

    const float bb = bias[j];
#pragma unroll 1
    for (int r = 0; r < 16; ++r) {
        const long m = m0 + sg * 16 + r;
        if (m < (long)B_ * Tc) {
            const uint4* xr = xt + (sg * 16 + r) * KW;
            float a0 = 0.f, a1 = 0.f, a2 = 0.f, a3 = 0.f;
#pragma unroll
            for (int i = 0; i < KW; ++i) {
                uint4 h = xr[i];   // wave-uniform LDS broadcast
                uint4 ww = w[i];
                a0 = dot2(ww.x, h.x, a0);
                a1 = dot2(ww.y, h.y, a1);
                a2 = dot2(ww.z, h.z, a2);
                a3 = dot2(ww.w, h.w, a3);
            }
            outx[m * H_ + j] = (_Float16)(((a0 + a1) + (a2 + a3)) + bb);
        }
    }
}

// ---- single-layer scan: h[t] = tanh(Whh h[t-1] + xw[t]) ------------------
// 512 threads = 8 waves, ALL compute; lane -> output jj = wv*32+(lane&31),
// K-half = lane>>5. Weights = 128 f16 = 64 VGPRs (arch-resident regime).
// Cross-half partial exchange via permlane32_swap (VALU, no LDS hop).
// h-chunk overwrites consumed xw slot in the LDS stage (half==1 lane);
// bulk coalesced global copy after the loop.
__device__ __forceinline__ void scan_layer(const _Float16* __restrict__ xw,
                                           const _Float16* __restrict__ Whh,
                                           _Float16* __restrict__ carry,
                                           _Float16* __restrict__ hout,
                                           char* __restrict__ sm, int b,
                                           int tid, int Tc) {
    __builtin_amdgcn_s_setprio(1);                // scan waves win VALU arbitration
    _Float16* stage = (_Float16*)sm;              // [Tc][256] (<= 32 KB)
    _Float16* hbuf  = (_Float16*)(sm + TCMAX * H_ * 2);  // [2][256]
    const int wv = tid >> 6, lane = tid & 63, half = lane >> 5;
    const int jj = wv * 32 + (lane & 31);

    uint4 w[16];   // 128 f16: row jj, K-half
    {
        const uint4* wp = (const uint4*)(Whh + (long)jj * H_ + half * 128);
#pragma unroll
        for (int i = 0; i < 16; ++i) w[i] = wp[i];
    }

    {   // stage the whole xw chunk: zero global loads in the loop
        const uint4* src = (const uint4*)(xw + (long)b * Tc * H_);
        uint4* dst = (uint4*)stage;
        for (int i = tid; i < Tc * (H_ / 8); i += 512) dst[i] = src[i];
    }
    if (tid < 256) hbuf[tid] = carry[b * H_ + tid];
    __syncthreads();   // full drain once (stage loads + carry init)

    float hlast = 0.f;
#pragma unroll 1
    for (int it = 0; it < Tc; ++it) {
        const int p = it & 1;
        float xh = (float)stage[it * H_ + jj];     // broadcast pair read
        const uint4* hb = (const uint4*)(hbuf + p * H_) + half * 16;
        float a0 = 0.f, a1 = 0.f, a2 = 0.f, a3 = 0.f;
#pragma unroll
        for (int i = 0; i < 16; ++i) {
            uint4 h = hb[i];   // 2-addr broadcast read: conflict-free
            uint4 ww = w[i];
            a0 = dot2(ww.x, h.x, a0);
            a1 = dot2(ww.y, h.y, a1);
            a2 = dot2(ww.z, h.z, a2);
            a3 = dot2(ww.w, h.w, a3);
        }
        float s = (a0 + a1) + (a2 + a3);
        s += half_partner(s, lane);                // VALU cross-half exchange
        float hv = fast_tanh(s + xh);
        _Float16 hf = (_Float16)hv;
        if (half == 0) hbuf[(p ^ 1) * H_ + jj] = hf;  // state for next step
        else           stage[it * H_ + jj]     = hf;  // h in place of xw
        hlast = hv;
        lds_barrier();   // ALL 8 waves, every iteration
    }

    if (half == 0) carry[b * H_ + jj] = (_Float16)hlast;
    {   // bulk coalesced h-chunk write (off the critical path)
        const uint4* src = (const uint4*)stage;
        uint4* dst = (uint4*)(hout + (long)b * Tc * H_);
        for (int i = tid; i < Tc * (H_ / 8); i += 512) dst[i] = src[i];
    }
}

// ---- transpose (512 thr): h1 [b][tc][j] f16 -> out [b][j][t0+tc] ---------
__device__ __forceinline__ void transpose_dev(const _Float16* __restrict__ tmp,
                                              void* __restrict__ out,
                                              const int* __restrict__ flag,
                                              int t0, int Tc, int pb,
                                              char* __restrict__ sm, int tid) {
    const int nTc = (Tc + 63) >> 6;
    int bid = pb;
    const int jblk = bid & 3; bid >>= 2;      // H_/64 == 4
    const int tcblk = bid % nTc;
    const int b = bid / nTc;
    const bool f32o = (*flag != 0);
    float* tile = (float*)sm;                 // [64][65]
#pragma unroll
    for (int k = 0; k < 8; ++k) {
        int idx = k * 512 + tid;
        int r = idx >> 6, c = idx & 63;
        int tc = tcblk * 64 + r;
        tile[r * 65 + c] = (tc < Tc)
            ? (float)tmp[((long)b * Tc + tc) * H_ + jblk * 64 + c] : 0.f;
    }
    __syncthreads();
#pragma unroll
    for (int k = 0; k < 8; ++k) {
        int idx = k * 512 + tid;
        int jr = idx >> 6, tc = idx & 63;
        if (tcblk * 64 + tc < Tc) {
            float v = tile[tc * 65 + jr];
            long o = ((long)b * H_ + jblk * 64 + jr) * (long)T_ + t0 + tcblk * 64 + tc;
            if (f32o) ((float*)out)[o] = v;
            else      ((__hip_bfloat16*)out)[o] = __float2bfloat16(v);
        }
    }
}

// ---- boot: proj0 of chunk 0 ----------------------------------------------
__global__ __launch_bounds__(512, 1) void boot(
    const void* __restrict__ x, const _Float16* __restrict__ W,
    const float* __restrict__ bias, _Float16* __restrict__ outx,
    const int* __restrict__ flag, int Tc)
{
    __shared__ __align__(16) char sm[16384];
    proj_gemm<D_, true>(x, W, bias, outx, flag, 0, Tc, blockIdx.x, sm, threadIdx.x);
}

// ---- mega: scan0(d) || scan1(d-2) || proj0(d+1) || proj1(d-1) || tr(d-3) -
__global__ __launch_bounds__(512, 1) void mega(
    const void* __restrict__ x,
    const _Float16* __restrict__ Wih0, const _Float16* __restrict__ Whh0,
    const _Float16* __restrict__ Wih1, const _Float16* __restrict__ Whh1,
    const float* __restrict__ bias0, const float* __restrict__ bias1,
    _Float16* __restrict__ carry0, _Float16* __restrict__ carry1,
    const _Float16* __restrict__ xw0r, _Float16* __restrict__ xw0w,
    _Float16* __restrict__ h0w, const _Float16* __restrict__ h0r,
    _Float16* __restrict__ xw1w, const _Float16* __restrict__ xw1r,
    _Float16* __restrict__ h1w, const _Float16* __restrict__ h1r,
    void* __restrict__ dout, const int* __restrict__ flag,
    int v_s0, int t_p0, int v_p1, int v_s1, int t_tr, int Tc, int nproj)
{
    // > 80 KiB: 1 block/CU (scan CUs isolated from GEMM blocks).
    __shared__ __align__(16) char sm[SMEM_BYTES];
    const int bid = blockIdx.x;
    const int tid = threadIdx.x;

    if (bid < 64) {                              // scan0 chunk d
        if (!v_s0) return;
        scan_layer(xw0r, Whh0, carry0, h0w, sm, bid, tid, Tc);
    } else if (bid < 128) {                      // scan1 chunk d-2
        if (!v_s1) return;
        scan_layer(xw1r, Whh1, carry1, h1w, sm, bid - 64, tid, Tc);
    } else if (bid < 128 + nproj) {              // proj0 chunk d+1
        if (t_p0 < 0) return;
        proj_gemm<D_, true>(x, Wih0, bias0, xw0w, flag, t_p0, Tc, bid - 128, sm, tid);
    } else if (bid < 128 + 2 * nproj) {          // proj1 chunk d-1
        if (!v_p1) return;
        proj_gemm<H_, false>(h0r, Wih1, bias1, xw1w, flag, 0, Tc, bid - 128 - nproj, sm, tid);
    } else {                                     // transpose chunk d-3
        if (t_tr < 0) return;
        transpose_dev(h1r, dout, flag, t_tr, Tc, bid - 128 - 2 * nproj, sm, tid);
    }
}

// ---------------------------------------------------------------------------
extern "C" void kernel_launch(void* const* d_in, const int* in_sizes, int n_in,
                              void* d_out, int out_size, void* d_ws, size_t ws_size,
                              hipStream_t stream) {
    const void* x    = d_in[0];
    const void* wih0 = d_in[1];
    const void* whh0 = d_in[2];
    const void* bih0 = d_in[3];
    const void* bhh0 = d_in[4];
    const void* wih1 = d_in[5];
    const void* whh1 = d_in[6];
    const void* bih1 = d_in[7];
    const void* bhh1 = d_in[8];
    (void)in_sizes; (void)n_in; (void)out_size;

    char* ws = (char*)d_ws;
    size_t off = 0;
    auto alloc = [&](size_t bytes) -> void* {
        void* p = ws + off;
        off += (bytes + 255) & ~(size_t)255;
        return p;
    };

    int*      flag    = (int*)alloc(256);
    _Float16* wih0_16 = (_Float16*)alloc((size_t)H_ * D_ * 2);
    _Float16* whh0_16 = (_Float16*)alloc((size_t)H_ * H_ * 2);
    _Float16* wih1_16 = (_Float16*)alloc((size_t)H_ * H_ * 2);
    _Float16* whh1_16 = (_Float16*)alloc((size_t)H_ * H_ * 2);
    float*    bias0   = (float*)alloc(H_ * 4);
    float*    bias1   = (float*)alloc(H_ * 4);
    _Float16* carry0  = (_Float16*)alloc((size_t)B_ * H_ * 2);   // must stay
    _Float16* carry1  = (_Float16*)alloc((size_t)B_ * H_ * 2);   // adjacent

    size_t fixed = off;
    // largest Tc (<=TCMAX) whose EIGHT chunk buffers fit in ws
    int Tc = TCMAX;
    while (Tc > 16 && fixed + 8 * ((size_t)B_ * Tc * H_ * 2 + 256) > ws_size) Tc >>= 1;
    _Float16 *xw0g[2], *xw1g[2], *h0g[2], *h1g[2];
    for (int i = 0; i < 2; ++i) xw0g[i] = (_Float16*)alloc((size_t)B_ * Tc * H_ * 2);
    for (int i = 0; i < 2; ++i) xw1g[i] = (_Float16*)alloc((size_t)B_ * Tc * H_ * 2);
    for (int i = 0; i < 2; ++i) h0g[i]  = (_Float16*)alloc((size_t)B_ * Tc * H_ * 2);
    for (int i = 0; i < 2; ++i) h1g[i]  = (_Float16*)alloc((size_t)B_ * Tc * H_ * 2);

    detect_dtype<<<1, 64, 0, stream>>>((const unsigned short*)whh0, flag);
    prep_w<<<(H_ * H_ + 255) / 256, 256, 0, stream>>>(
        wih0, whh0, bih0, bhh0, wih1, whh1, bih1, bhh1,
        wih0_16, whh0_16, wih1_16, whh1_16, bias0, bias1, (uint4*)carry0, flag);

    const int NC     = T_ / Tc;
    const int nproj  = (B_ * Tc + 31) / 32;
    const int ntrans = B_ * ((Tc + 63) / 64) * (H_ / 64);
    const int grid   = 128 + 2 * nproj + ntrans;

    boot<<<nproj, 512, 0, stream>>>(x, wih0_16, bias0, xw0g[0], flag, Tc);

    for (int d = 0; d <= NC + 2; ++d) {
        const int v_s0 = (d < NC) ? 1 : 0;                       // scan0 chunk d
        const int t_p0 = (d + 1 < NC) ? (d + 1) * Tc : -1;       // proj0 chunk d+1
        const int v_p1 = (d - 1 >= 0 && d - 1 < NC) ? 1 : 0;     // proj1 chunk d-1
        const int v_s1 = (d - 2 >= 0 && d - 2 < NC) ? 1 : 0;     // scan1 chunk d-2
        const int t_tr = (d - 3 >= 0 && d - 3 < NC) ? (d - 3) * Tc : -1;
        mega<<<grid, 512, 0, stream>>>(
            x, wih0_16, whh0_16, wih1_16, whh1_16, bias0, bias1,
            carry0, carry1,
            xw0g[d & 1],            // scan0 reads chunk d
            xw0g[(d + 1) & 1],      // proj0 writes chunk d+1
            h0g[d & 1],             // scan0 writes chunk d
            h0g[(d - 1) & 1],       // proj1 reads chunk d-1
            xw1g[(d - 1) & 1],      // proj1 writes chunk d-1
            xw1g[(d - 2) & 1],      // scan1 reads chunk d-2
            h1g[(d - 2) & 1],       // scan1 writes chunk d-2
            h1g[(d - 3) & 1],       // transpose reads chunk d-3
            d_out, flag, v_s0, t_p0, v_p1, v_s1, t_tr, Tc, nproj);
    }
}